// Round 6
// baseline (42.654 us; speedup 1.0000x reference)
//
#include <hip/hip_runtime.h>

#define SCALE 28.853900817779268f   // 20*log2(e)
#define L2E   1.4426950408889634f   // log2(e)
#define M 2048                      // histogram bins over p in [0,1]
#define T 1024                      // threads per block
#define CPC 32                      // chunk-blocks per class (phase 2)
#define QB (M/CPC)                  // 64 mk-bins per block (STRIDED: mk = ch + CPC*q)
#define NBLK 256                    // grid size (8 classes x 32 chunks)
#define GUARD (1<<16)               // bounded spins: fail-wrong, never hang
#define MAGIC0 0x5ACEB007u          // 64-bit canary: poison cannot fake both words
#define MAGIC1 0xC0FFEE42u

__device__ __forceinline__ float fexp2(float x){ return __builtin_amdgcn_exp2f(x); }
__device__ __forceinline__ float frcp (float x){ return __builtin_amdgcn_rcpf(x); }

#define WRED64(x) { _Pragma("unroll") for (int _o = 32; _o; _o >>= 1) x += __shfl_down(x, _o, 64); }

#define ALOAD(p)    __hip_atomic_load((p), __ATOMIC_RELAXED, __HIP_MEMORY_SCOPE_AGENT)
#define ASTORE(p,v) __hip_atomic_store((p),(v), __ATOMIC_RELAXED, __HIP_MEMORY_SCOPE_AGENT)
#define AADD(p,v)   __hip_atomic_fetch_add((p),(v), __ATOMIC_RELAXED, __HIP_MEMORY_SCOPE_AGENT)

// 256 blocks = 8 classes x 32 chunks. R5 lesson: out[] is only zeroed on the
// accuracy launch; timed-graph replays and post-reset tripwires get stale out
// -> NEVER sync on out. This version is fully self-contained:
//  * 64-bit MAGIC canary detects poisoned workspace; block 0 zeroes both hist
//    buffers + sync words and publishes magic (others spin, bounded).
//  * base-agnostic global barrier: o=AADD(abar); o%256==255 publishes hrel=o+1;
//    spin (int)(hrel-o)<=0. Works for any base = 0 mod 256 (init guarantees,
//    +256/launch preserves).
//  * Ghist DOUBLE-BUFFERED by launch parity (abar>>8)&1: flush into buf[par],
//    zero own 64-word share of buf[par^1] for the NEXT launch -> no
//    cross-launch accumulation (the R5 bug), no read-vs-zero race.
//  * phase 1 visits each row ONCE computing all 8 class bins from one exp-set
//    (8192 visits vs 65536): 1.2 KB read + 8 global int atomicAdds per row.
// Integer histogram -> bit-deterministic; init/non-init paths bit-identical.
__global__ __launch_bounds__(1024)
void k_fused(const float* __restrict__ logits, const int* __restrict__ tgt,
             float* __restrict__ out, unsigned* __restrict__ sync,
             float* __restrict__ gpart, int* __restrict__ ccnt,
             int* __restrict__ Ghist, int N){
  const int b = blockIdx.x, NB = (int)gridDim.x;
  const int c = b >> 5, ch = b & (CPC-1);
  const int tid = threadIdx.x, lane = tid & 63, w = tid >> 6;
  const float invM = 1.0f / (float)M;
  unsigned* ticket = sync + 0;       // finalize ticket (mod-NB, any base)
  unsigned* abar   = sync + 1;       // barrier arrivals (monotonic)
  unsigned* hrel   = sync + 2;       // barrier release (monotonic publish)
  unsigned* magic  = sync + 4;       // [4],[5] canary

  __shared__ int   HP[M];            // full class hist after readback
  __shared__ float Bq[QB];
  __shared__ int   wnp[16];
  __shared__ float rw[16];
  __shared__ float scs[8];
  __shared__ int   initflag, parS, lastflag;

  // ---- tables (register/LDS only; overlaps the gate) ----
  float Ej0 = fexp2(-SCALE * ((float)tid       + 0.5f) * invM);
  float Ej1 = fexp2(-SCALE * ((float)(tid + T) + 0.5f) * invM);
  if (tid < QB)
    Bq[tid] = fexp2(SCALE * ((float)(ch + CPC*tid) + 0.5f) * invM);

  // ---- phase-1 row compute in registers: this block's 32 rows, ALL classes --
  const int R = (N + NBLK - 1) / NBLK;   // 32 rows per block
  const bool havework = (tid < R) && (b*R + tid < N);
  int bn0=0,bn1=0,bn2=0,bn3=0,bn4=0,bn5=0,bn6=0,bn7=0, tv=-1;
  if (havework){
    int i = b*R + tid;
    const float4* l4 = (const float4*)logits;
    float4 A = l4[2*i], B4 = l4[2*i+1];
    float e0=fexp2(A.x *L2E), e1=fexp2(A.y *L2E), e2=fexp2(A.z *L2E), e3=fexp2(A.w *L2E);
    float e4=fexp2(B4.x*L2E), e5=fexp2(B4.y*L2E), e6=fexp2(B4.z*L2E), e7=fexp2(B4.w*L2E);
    float s = ((e0+e1)+(e2+e3))+((e4+e5)+(e6+e7));
    float r = frcp(s) * (float)M;         // p_c*M = e_c * r
    bn0=min((int)(e0*r),M-1); bn1=min((int)(e1*r),M-1);
    bn2=min((int)(e2*r),M-1); bn3=min((int)(e3*r),M-1);
    bn4=min((int)(e4*r),M-1); bn5=min((int)(e5*r),M-1);
    bn6=min((int)(e6*r),M-1); bn7=min((int)(e7*r),M-1);
    tv = tgt[i];
  }

  // ---- epoch gate: canary check, block-0 init if poisoned ----
  if (tid == 0)
    initflag = (ALOAD(magic) != MAGIC0) || (ALOAD(magic+1) != MAGIC1);
  __syncthreads();
  if (initflag){
    if (b == 0){
      for (int m = tid; m < 2*8*M; m += T) ASTORE(&Ghist[m], 0);  // both buffers
      if (tid < 4) ASTORE(&sync[tid], 0u);   // ticket, abar, hrel, spare
      __syncthreads();                       // zero stores drained (wave vmcnt)
      if (tid == 0){
        __threadfence();                     // release zeros
        ASTORE(magic, MAGIC0); ASTORE(magic+1, MAGIC1);
      }
    } else if (tid == 0){
      int g = 0;
      while ((ALOAD(magic) != MAGIC0 || ALOAD(magic+1) != MAGIC1) && ++g < GUARD)
        __builtin_amdgcn_s_sleep(8);
      __threadfence();                       // acquire
    }
  }
  __syncthreads();                           // whole block gated

  // ---- parity (read BEFORE own arrival -> uniform: abar < base+256 here) ----
  if (tid == 0) parS = (int)((ALOAD(abar) >> 8) & 1u);
  __syncthreads();
  const int par = parS;
  int* __restrict__ Gb = Ghist + par*(8*M);
  {                                          // zero my share of the OTHER buffer
    int* ob = Ghist + (par^1)*(8*M) + b*64;
    if (tid < 64) ASTORE(&ob[tid], 0);
  }
  if (havework){                             // sparse flush: 8 adds per row
    AADD(&Gb[0*M+bn0], 1 + ((tv==0)?(1<<16):0));
    AADD(&Gb[1*M+bn1], 1 + ((tv==1)?(1<<16):0));
    AADD(&Gb[2*M+bn2], 1 + ((tv==2)?(1<<16):0));
    AADD(&Gb[3*M+bn3], 1 + ((tv==3)?(1<<16):0));
    AADD(&Gb[4*M+bn4], 1 + ((tv==4)?(1<<16):0));
    AADD(&Gb[5*M+bn5], 1 + ((tv==5)?(1<<16):0));
    AADD(&Gb[6*M+bn6], 1 + ((tv==6)?(1<<16):0));
    AADD(&Gb[7*M+bn7], 1 + ((tv==7)?(1<<16):0));
  }
  __syncthreads();                           // all waves' adds/zeros drained

  // ---- global barrier (base-agnostic) ----
  if (tid == 0){
    __threadfence();                         // release flush
    unsigned o = AADD(abar, 1u);
    if ((o & (NBLK-1)) == (NBLK-1)){         // unique last arriver
      __threadfence();
      ASTORE(hrel, o + 1u);                  // monotonic release publish
    } else {
      int g = 0;
      while ((int)(ALOAD(hrel) - o) <= 0 && ++g < GUARD)
        __builtin_amdgcn_s_sleep(2);
    }
    __threadfence();                         // acquire
  }
  __syncthreads();                           // full histogram now readable

  // ---- readback full class-c histogram; extract fragments ----
  int np_part; float Hj0, Hj1;
  {
    int* Gc = Gb + c*M;
    int g0 = ALOAD(&Gc[tid]);
    int g1 = ALOAD(&Gc[tid + T]);
    HP[tid]     = g0;                        // LDS copy for phase-2 broadcasts
    HP[tid + T] = g1;
    int p0 = g0 >> 16, p1 = g1 >> 16;
    np_part = p0 + p1;
    Hj0 = (float)((g0 & 0xFFFF) - p0);
    Hj1 = (float)((g1 & 0xFFFF) - p1);
  }
  WRED64(np_part)
  if (lane == 0) wnp[w] = np_part;
  __syncthreads();                           // HP full + wnp visible

  // ---- phase 2: pair partial over this block's 64 STRIDED mk-bins ----
  float tot = 0.f;
  #pragma unroll 4
  for (int q = 0; q < QB; ++q){
    int Pki = HP[ch + CPC*q] >> 16;          // LDS uniform broadcast
    if (Pki == 0) continue;                  // wave-uniform skip
    float Bk = Bq[q];
    float Pk = (float)Pki;
    float s0 = Hj0 * frcp(fmaf(Bk, Ej0, 1.0f));
    float s1 = Hj1 * frcp(fmaf(Bk, Ej1, 1.0f));
    tot += Pk * (s0 + s1);
  }
  WRED64(tot)
  if (lane == 0) rw[w] = tot;
  __syncthreads();
  if (tid == 0){
    float bt = 0.f;
    #pragma unroll
    for (int i = 0; i < 16; ++i) bt += rw[i];
    atomicExch(&gpart[b], bt);               // overwrite -> stale-safe
    if (ch == 0){                            // one writer/class; np identical
      int snp = 0;
      #pragma unroll
      for (int i = 0; i < 16; ++i) snp += wnp[i];
      atomicExch(&ccnt[c], snp);
    }
    __threadfence();                         // release
    unsigned old = atomicAdd(ticket, 1u);    // mod-NB: any base, unique winner
    lastflag = ((old % (unsigned)NB) == (unsigned)(NB - 1));
  }
  __syncthreads();
  if (!lastflag) return;

  // ---- finalize (last block; fixed order -> deterministic) ----
  if (tid == 0) __threadfence();             // acquire
  __syncthreads();
  if (tid < 256){
    int c2 = tid >> 5, l = tid & 31;
    float s = atomicAdd(&gpart[c2*CPC + l], 0.0f);   // coherent read
    #pragma unroll
    for (int o = 16; o; o >>= 1) s += __shfl_down(s, o, 32);
    if (l == 0) scs[c2] = s;
  }
  __syncthreads();
  if (tid < 8){
    int np = atomicAdd(&ccnt[tid], 0);
    int nn = N - np;
    bool valid = (np > 0 && nn > 0);
    float t = valid ? scs[tid] / ((float)np * (float)nn) : 0.f;
    float f = valid ? 1.f : 0.f;
    #pragma unroll
    for (int o = 4; o; o >>= 1){
      t += __shfl_down(t, o, 8);
      f += __shfl_down(f, o, 8);
    }
    if (tid == 0) out[0] = (f > 0.f) ? (1.0f - t / f) : 0.0f;
  }
}

extern "C" void kernel_launch(void* const* d_in, const int* in_sizes, int n_in,
                              void* d_out, int out_size, void* d_ws, size_t ws_size,
                              hipStream_t stream) {
    const float* logits = (const float*)d_in[0];
    const int*   tgt    = (const int*)d_in[1];
    float* out = (float*)d_out;
    int N = in_sizes[1];

    unsigned* sync  = (unsigned*)d_ws;                 // [0..5] ticket/abar/hrel/magic
    float*    gpart = (float*)d_ws + 32;               // [32..287] block partials
    int*      ccnt  = (int*)((float*)d_ws + 288);      // [288..295]
    int*      Ghist = (int*)((float*)d_ws + 512);      // 2 buffers x 8*M ints

    k_fused<<<NBLK, T, 0, stream>>>(logits, tgt, out, sync, gpart, ccnt, Ghist, N);
}

// Round 7
// 19.680 us; speedup vs baseline: 2.1673x; 2.1673x over previous
//
#include <hip/hip_runtime.h>

#define SCALE 28.853900817779268f   // 20*log2(e)
#define L2E   1.4426950408889634f   // log2(e)
#define M 2048                      // histogram bins over p in [0,1]
#define T 1024                      // threads per block
#define CPC 32                      // blocks per class
#define QB (M/CPC)                  // 64 mk-bins per block (STRIDED: mk = ch + CPC*q)
#define NC 8                        // privatized LDS histogram copies

__device__ __forceinline__ float fexp2(float x){ return __builtin_amdgcn_exp2f(x); }
__device__ __forceinline__ float frcp (float x){ return __builtin_amdgcn_rcpf(x); }

#define WRED64(x) { _Pragma("unroll") for (int _o = 32; _o; _o >>= 1) x += __shfl_down(x, _o, 64); }

// REVERT to the R3 structure (last fast passing kernel, 18.7us): 256 blocks =
// 8 classes x 32 chunks; each block redundantly histograms ALL rows for its
// class through L2-cached vector loads + LDS integer atomics (R6 proved the
// global-merge alternative costs ~25us in uncoalesced device-scope traffic).
// NEW: 8-way PRIVATIZED histogram copies (wave w -> copy w>>1) to cut hot-bin
// same-address serialization ~8x; fixed-order integer merge at extraction ->
// bit-identical histogram to R3 (absmax must stay exactly 0.0078125).
// Plus unroll-4 on the row loop for outstanding-load ILP.
// Workspace use is poison-safe exactly as R3: gpart/ccnt are overwrite-only
// (atomicExch), finalize elected by persistent mod-NB ticket.
__global__ __launch_bounds__(1024)
void k_fused(const float* __restrict__ logits, const int* __restrict__ tgt,
             float* __restrict__ out, unsigned* __restrict__ ticket,
             float* __restrict__ gpart, int* __restrict__ ccnt, int N){
  const int b = blockIdx.x, NB = (int)gridDim.x;
  const int c = b >> 5, ch = b & (CPC-1);
  const int tid = threadIdx.x, lane = tid & 63, w = tid >> 6;
  const float invM = 1.0f / (float)M;

  __shared__ int   HP[NC*M];         // 8 privatized copies; copy 0 holds merge
  __shared__ float Bq[QB];
  __shared__ int   wnp[16];
  __shared__ float rw[16];
  __shared__ float scs[8];
  __shared__ int   lastflag;

  // setup: zero all copies (int4 = 16 B/thread x4), hoist transcendentals
  {
    int4 z = make_int4(0,0,0,0);
    int4* h4 = (int4*)HP;            // NC*M/4 = 4096 int4s
    h4[tid] = z; h4[tid+1024] = z; h4[tid+2048] = z; h4[tid+3072] = z;
  }
  float Ej0 = fexp2(-SCALE * ((float)tid       + 0.5f) * invM);
  float Ej1 = fexp2(-SCALE * ((float)(tid + T) + 0.5f) * invM);
  if (tid < QB)
    Bq[tid] = fexp2(SCALE * ((float)(ch + CPC*tid) + 0.5f) * invM);
  __syncthreads();

  // ---- phase 1: class-c histogram over ALL rows, privatized by wave-pair ----
  int* Hw = HP + (w >> 1) * M;       // this wave's copy
  const float4* l4 = (const float4*)logits;
  #pragma unroll 4
  for (int i = tid; i < N; i += T){
    float4 A = l4[2*i], B4 = l4[2*i+1];
    float y0=A.x *L2E, y1=A.y *L2E, y2=A.z *L2E, y3=A.w *L2E;
    float y4=B4.x*L2E, y5=B4.y*L2E, y6=B4.z*L2E, y7=B4.w*L2E;
    float yc = y0;                   // static select of class-c value
    yc=(c==1)?y1:yc; yc=(c==2)?y2:yc; yc=(c==3)?y3:yc;
    yc=(c==4)?y4:yc; yc=(c==5)?y5:yc; yc=(c==6)?y6:yc; yc=(c==7)?y7:yc;
    float s = ((fexp2(y0-yc)+fexp2(y1-yc)) + (fexp2(y2-yc)+fexp2(y3-yc)))
            + ((fexp2(y4-yc)+fexp2(y5-yc)) + (fexp2(y6-yc)+fexp2(y7-yc)));
    float p = frcp(s);               // p_c = 1/sum (bit-identical to R3)
    int bin = min((int)(p * (float)M), M-1);
    int inc = 1 + ((tgt[i] == c) ? (1 << 16) : 0);
    atomicAdd(&Hw[bin], inc);        // LDS, integer, 1/8 the contention
  }
  __syncthreads();

  // ---- merge copies (fixed order -> bit-deterministic) + extract fragments --
  float Hj0, Hj1; int np_part;
  {
    int hp0 = 0, hp1 = 0;
    #pragma unroll
    for (int k = 0; k < NC; ++k){
      hp0 += HP[k*M + tid];
      hp1 += HP[k*M + tid + T];
    }
    HP[tid]     = hp0;               // merged -> copy 0 (own words only; safe)
    HP[tid + T] = hp1;
    int p0 = hp0 >> 16, p1 = hp1 >> 16;
    np_part = p0 + p1;
    Hj0 = (float)((hp0 & 0xFFFF) - p0);
    Hj1 = (float)((hp1 & 0xFFFF) - p1);
  }
  WRED64(np_part)
  if (lane == 0) wnp[w] = np_part;
  __syncthreads();                   // merged copy 0 + wnp visible

  // ---- phase 2: pair partial over this block's 64 STRIDED mk-bins ----
  float tot = 0.f;
  #pragma unroll 4
  for (int q = 0; q < QB; ++q){
    int Pki = HP[ch + CPC*q] >> 16;  // LDS uniform broadcast (merged copy)
    if (Pki == 0) continue;          // wave-uniform skip
    float Bk = Bq[q];
    float Pk = (float)Pki;
    float s0 = Hj0 * frcp(fmaf(Bk, Ej0, 1.0f));
    float s1 = Hj1 * frcp(fmaf(Bk, Ej1, 1.0f));
    tot += Pk * (s0 + s1);
  }
  WRED64(tot)
  if (lane == 0) rw[w] = tot;
  __syncthreads();
  if (tid == 0){
    float bt = 0.f;
    #pragma unroll
    for (int i = 0; i < 16; ++i) bt += rw[i];
    atomicExch(&gpart[b], bt);       // overwrite -> poison/stale-safe
    if (ch == 0){                    // one writer/class; np identical in all
      int snp = 0;
      #pragma unroll
      for (int i = 0; i < 16; ++i) snp += wnp[i];
      atomicExch(&ccnt[c], snp);
    }
    __threadfence();                 // release
    unsigned old = atomicAdd(ticket, 1u);  // persistent mod-NB ticket
    lastflag = ((old % (unsigned)NB) == (unsigned)(NB - 1));
  }
  __syncthreads();
  if (!lastflag) return;

  // ---- finalize (last block; fixed order -> deterministic) ----
  if (tid == 0) __threadfence();     // acquire
  __syncthreads();
  if (tid < 256){
    int c2 = tid >> 5, l = tid & 31;
    float s = atomicAdd(&gpart[c2*CPC + l], 0.0f);   // coherent read
    #pragma unroll
    for (int o = 16; o; o >>= 1) s += __shfl_down(s, o, 32);
    if (l == 0) scs[c2] = s;
  }
  __syncthreads();
  if (tid < 8){
    int np = atomicAdd(&ccnt[tid], 0);
    int nn = N - np;
    bool valid = (np > 0 && nn > 0);
    float t = valid ? scs[tid] / ((float)np * (float)nn) : 0.f;
    float f = valid ? 1.f : 0.f;
    #pragma unroll
    for (int o = 4; o; o >>= 1){
      t += __shfl_down(t, o, 8);
      f += __shfl_down(f, o, 8);
    }
    if (tid == 0) out[0] = (f > 0.f) ? (1.0f - t / f) : 0.0f;
  }
}

extern "C" void kernel_launch(void* const* d_in, const int* in_sizes, int n_in,
                              void* d_out, int out_size, void* d_ws, size_t ws_size,
                              hipStream_t stream) {
    const float* logits = (const float*)d_in[0];
    const int*   tgt    = (const int*)d_in[1];
    float* out = (float*)d_out;
    int N = in_sizes[1];

    unsigned* ticket = (unsigned*)d_ws;                // [0] persistent mod-NB
    float* gpart = (float*)d_ws + 32;                  // [32..287] block partials
    int*   ccnt  = (int*)((float*)d_ws + 288);         // [288..295]

    k_fused<<<8*CPC, T, 0, stream>>>(logits, tgt, out, ticket, gpart, ccnt, N);
}

// Round 8
// 18.720 us; speedup vs baseline: 2.2785x; 1.0513x over previous
//
#include <hip/hip_runtime.h>

#define SCALE 28.853900817779268f   // 20*log2(e)
#define L2E   1.4426950408889634f   // log2(e)
#define M 2048                      // histogram bins over p in [0,1]
#define T 1024                      // threads per block
#define CPC 32                      // blocks per class
#define QB (M/CPC)                  // 64 mk-bins per block (STRIDED: mk = ch + CPC*q)

__device__ __forceinline__ float fexp2(float x){ return __builtin_amdgcn_exp2f(x); }
__device__ __forceinline__ float frcp (float x){ return __builtin_amdgcn_rcpf(x); }

#define WRED64(x) { _Pragma("unroll") for (int _o = 32; _o; _o >>= 1) x += __shfl_down(x, _o, 64); }
#define ALOAD(p) __hip_atomic_load((p), __ATOMIC_RELAXED, __HIP_MEMORY_SCOPE_AGENT)

// R3 structure (best passing: 18.7us): 256 blocks = 8 classes x 32 chunks;
// each block redundantly histograms ALL rows for its class (L2-fed float4
// loads + single LDS int histogram -- R7 proved privatization is a net loss).
// NEW this round:
//  * g-TABLE phase 2: the pair term depends only on bin DIFFERENCE d=mk-mj
//    (the +0.5 offsets cancel), so a 4095-entry LDS table g[d+2047] =
//    1/(1+2^(S*d/M)) -- built with 4 transcendentals/thread -- replaces the
//    2 v_rcp per inner iteration with 2 conflict-free ds_read_b32. Formula
//    sign is EXACTLY the verified one (g reproduces frcp(fmaf(Bk,Ej,1))).
//  * phase 1 drops the yc-subtraction: exps of yj directly (|yj|<9, safe),
//    ec selected from the computed exps, p = ec*rcp(s).
//  * finalize reads gpart/ccnt with agent-scope LOADS (no RMW serialization)
//    under the unchanged fence/ticket handshake.
// Integer histogram -> bit-deterministic. Workspace poison-safe as R3:
// gpart/ccnt overwrite-only (atomicExch), finalize elected by mod-NB ticket.
__global__ __launch_bounds__(1024)
void k_fused(const float* __restrict__ logits, const int* __restrict__ tgt,
             float* __restrict__ out, unsigned* __restrict__ ticket,
             float* __restrict__ gpart, int* __restrict__ ccnt, int N){
  const int b = blockIdx.x, NB = (int)gridDim.x;
  const int c = b >> 5, ch = b & (CPC-1);
  const int tid = threadIdx.x, lane = tid & 63, w = tid >> 6;
  const float invM = 1.0f / (float)M;

  __shared__ int   HP[M];            // packed hist: low16 all rows, high16 pos
  __shared__ float g[2*M];           // g[d+2047], d = mk-mj in (-M, M)
  __shared__ int   wnp[16];
  __shared__ float rw[16];
  __shared__ float scs[8];
  __shared__ int   lastflag;

  // setup: zero histogram, build difference-sigmoid table (4 trans/thread)
  ((int2*)HP)[tid] = make_int2(0, 0);
  #pragma unroll
  for (int r = 0; r < 4; ++r){
    int idx = tid + 1024*r;
    if (idx < 2*M-1){
      float d = (float)(idx - (M-1));
      g[idx] = frcp(1.0f + fexp2(SCALE * d * invM));  // == frcp(fmaf(Bk,Ej,1))
    }
  }
  __syncthreads();

  // ---- phase 1: class-c histogram over ALL rows ----
  const float4* l4 = (const float4*)logits;
  #pragma unroll 2
  for (int i = tid; i < N; i += T){
    float4 A = l4[2*i], B4 = l4[2*i+1];
    float e0=fexp2(A.x *L2E), e1=fexp2(A.y *L2E), e2=fexp2(A.z *L2E), e3=fexp2(A.w *L2E);
    float e4=fexp2(B4.x*L2E), e5=fexp2(B4.y*L2E), e6=fexp2(B4.z*L2E), e7=fexp2(B4.w*L2E);
    float s = ((e0+e1)+(e2+e3))+((e4+e5)+(e6+e7));
    float ec = e0;                   // static select of class-c exponential
    ec=(c==1)?e1:ec; ec=(c==2)?e2:ec; ec=(c==3)?e3:ec;
    ec=(c==4)?e4:ec; ec=(c==5)?e5:ec; ec=(c==6)?e6:ec; ec=(c==7)?e7:ec;
    float p = ec * frcp(s);          // p <= 1+ulp; min() guards the cast
    int bin = min((int)(p * (float)M), M-1);
    int inc = 1 + ((tgt[i] == c) ? (1 << 16) : 0);
    atomicAdd(&HP[bin], inc);        // LDS, integer -> deterministic
  }
  __syncthreads();

  // ---- fragment extraction: per thread 2 Hneg values + np partial ----
  float Hj0, Hj1; int np_part;
  {
    const int hp0 = HP[tid], hp1 = HP[tid + T];
    const int p0 = hp0 >> 16, p1 = hp1 >> 16;
    np_part = p0 + p1;
    Hj0 = (float)((hp0 & 0xFFFF) - p0);
    Hj1 = (float)((hp1 & 0xFFFF) - p1);
  }
  WRED64(np_part)
  if (lane == 0) wnp[w] = np_part;

  // ---- phase 2: pair partial over 64 STRIDED mk-bins via g-table ----
  float tot = 0.f;
  const int i0 = ch + (M-1) - tid;   // g-index for q=0, mj0=tid
  #pragma unroll 4
  for (int q = 0; q < QB; ++q){
    int Pki = HP[ch + CPC*q] >> 16;  // LDS uniform broadcast
    if (Pki == 0) continue;          // wave-uniform skip
    float g0 = g[i0 + CPC*q];        // mj0=tid    (consecutive lanes -> no conflict)
    float g1 = g[i0 + CPC*q - 1024]; // mj1=tid+1024
    tot += (float)Pki * fmaf(Hj0, g0, Hj1 * g1);
  }
  WRED64(tot)
  if (lane == 0) rw[w] = tot;
  __syncthreads();                   // rw + wnp visible
  if (tid == 0){
    float bt = 0.f;
    #pragma unroll
    for (int i = 0; i < 16; ++i) bt += rw[i];
    atomicExch(&gpart[b], bt);       // overwrite -> poison/stale-safe
    if (ch == 0){                    // one writer/class; np identical in all
      int snp = 0;
      #pragma unroll
      for (int i = 0; i < 16; ++i) snp += wnp[i];
      atomicExch(&ccnt[c], snp);
    }
    __threadfence();                 // release
    unsigned old = atomicAdd(ticket, 1u);  // persistent mod-NB ticket
    lastflag = ((old % (unsigned)NB) == (unsigned)(NB - 1));
  }
  __syncthreads();
  if (!lastflag) return;

  // ---- finalize (last block; fixed order -> deterministic) ----
  if (tid == 0) __threadfence();     // acquire
  __syncthreads();
  if (tid < 256){
    int c2 = tid >> 5, l = tid & 31;
    float s = ALOAD(&gpart[c2*CPC + l]);   // agent-scope load (no RMW)
    #pragma unroll
    for (int o = 16; o; o >>= 1) s += __shfl_down(s, o, 32);
    if (l == 0) scs[c2] = s;
  }
  __syncthreads();
  if (tid < 8){
    int np = ALOAD(&ccnt[tid]);
    int nn = N - np;
    bool valid = (np > 0 && nn > 0);
    float t = valid ? scs[tid] / ((float)np * (float)nn) : 0.f;
    float f = valid ? 1.f : 0.f;
    #pragma unroll
    for (int o = 4; o; o >>= 1){
      t += __shfl_down(t, o, 8);
      f += __shfl_down(f, o, 8);
    }
    if (tid == 0) out[0] = (f > 0.f) ? (1.0f - t / f) : 0.0f;
  }
}

extern "C" void kernel_launch(void* const* d_in, const int* in_sizes, int n_in,
                              void* d_out, int out_size, void* d_ws, size_t ws_size,
                              hipStream_t stream) {
    const float* logits = (const float*)d_in[0];
    const int*   tgt    = (const int*)d_in[1];
    float* out = (float*)d_out;
    int N = in_sizes[1];

    unsigned* ticket = (unsigned*)d_ws;                // [0] persistent mod-NB
    float* gpart = (float*)d_ws + 32;                  // [32..287] block partials
    int*   ccnt  = (int*)((float*)d_ws + 288);         // [288..295]

    k_fused<<<8*CPC, T, 0, stream>>>(logits, tgt, out, ticket, gpart, ccnt, N);
}